// Round 1
// baseline (406.024 us; speedup 1.0000x reference)
//
#include <hip/hip_runtime.h>
#include <hip/hip_bf16.h>
#include <cstdint>

#define DIM 128
#define ASTR 136   // LDS row stride (ushorts): 272 B, 16-B aligned, 2-way banks (free)
#define WSTR 136
#define NBKT 512   // dst buckets (dst>>8)
#define BCAP 4608  // per-bucket capacity: mean 3125 + ~26 sigma
#define ECHUNK 2500

typedef __bf16 bf16x8 __attribute__((ext_vector_type(8)));
typedef float  f32x4  __attribute__((ext_vector_type(4)));
typedef unsigned short u16x8 __attribute__((ext_vector_type(8)));
typedef unsigned short u16x4 __attribute__((ext_vector_type(4)));

__device__ __forceinline__ unsigned short f2bf(float f) {
    union { float f; unsigned u; } x; x.f = f;
    unsigned r = x.u + 0x7fffu + ((x.u >> 16) & 1u);   // RNE
    return (unsigned short)(r >> 16);
}
__device__ __forceinline__ float2 bfpair2f(unsigned v) {
    union { unsigned u; float f; } a, b;
    a.u = v << 16;
    b.u = v & 0xffff0000u;
    return make_float2(a.f, b.f);
}

__device__ __forceinline__ void load_edge(const unsigned* __restrict__ eidx,
                                          int e, int E, int is64,
                                          int& s, int& d) {
    if (is64) {
        s = (int)eidx[2 * (size_t)e];
        d = (int)eidx[2 * ((size_t)E + (size_t)e)];
    } else {
        s = (int)eidx[(size_t)e];
        d = (int)eidx[(size_t)E + (size_t)e];
    }
}

// ---------------------------------------------------------------------------
// prep_bin: ONE launch for edge binning + x->bf16 + W transpose + BN fold.
// Blocks [0,bblk) bin edges (each block self-detects idx dtype from the
// first 32 pairs); [bblk, bblk+xblk) convert x; [.., +wblk) transpose W;
// last block folds BN affine. gpos is zeroed by a prior memset (no
// cross-block ordering assumed).
// ---------------------------------------------------------------------------
__global__ __launch_bounds__(256) void prep_bin(
    const float* __restrict__ x,
    const float* __restrict__ W1, const float* __restrict__ W2,
    const float* __restrict__ b1, const float* __restrict__ g,
    const float* __restrict__ be, const float* __restrict__ m,
    const float* __restrict__ v, const unsigned* __restrict__ eidx,
    unsigned short* __restrict__ Wt, float* __restrict__ affA,
    float* __restrict__ affB, u16x4* __restrict__ P,
    int* __restrict__ gpos, unsigned* __restrict__ binned,
    int M, int E, int bblk, int xblk, int wblk)
{
    __shared__ int cnt[NBKT];
    __shared__ int bas[NBKT];
    __shared__ unsigned pk[ECHUNK];
    __shared__ unsigned short bkL[ECHUNK];
    const int b = blockIdx.x, t = threadIdx.x;

    if (b < bblk) {
        // ---- edge binning ----
        int is64 = 1;
        #pragma unroll 4
        for (int i = 0; i < 32; ++i)
            if (eidx[2 * i + 1] != 0u) { is64 = 0; break; }
        const int e0 = b * ECHUNK;
        int n = E - e0; if (n > ECHUNK) n = ECHUNK;

        for (int i = t; i < NBKT; i += 256) cnt[i] = 0;
        __syncthreads();
        for (int i = t; i < n; i += 256) {
            int s, d; load_edge(eidx, e0 + i, E, is64, s, d);
            int bk = d >> 8;
            pk[i] = ((unsigned)s << 8) | (unsigned)(d & 255);
            bkL[i] = (unsigned short)bk;
            atomicAdd(&cnt[bk], 1);
        }
        __syncthreads();
        for (int i = t; i < NBKT; i += 256) {
            int c = cnt[i];
            bas[i] = c ? atomicAdd(&gpos[i], c) : 0;
        }
        __syncthreads();
        for (int i = t; i < n; i += 256) {
            int bk = bkL[i];
            int slot = atomicAdd(&bas[bk], 1);
            if (slot < BCAP)
                binned[(size_t)bk * BCAP + slot] = pk[i];
        }
    } else if (b < bblk + xblk) {
        int id = (b - bblk) * 256 + t;
        if (id < M * 32) {
            float4 vv = ((const float4*)x)[id];
            u16x4 o;
            o[0] = f2bf(vv.x); o[1] = f2bf(vv.y);
            o[2] = f2bf(vv.z); o[3] = f2bf(vv.w);
            P[id] = o;
        }
    } else if (b < bblk + xblk + wblk) {
        int id = (b - bblk - xblk) * 256 + t;  // [0, 98304)
        int l = id / 32768;
        int r = id - l * 32768;
        int w = r >> 14;
        int idx = r & 16383;
        int k = idx >> 7, n = idx & 127;
        const float* src = (w ? W2 : W1) + (size_t)l * 16384;
        Wt[(size_t)id - idx + ((size_t)n * 128 + k)] = f2bf(src[k * 128 + n]);
    } else {
        for (int id = t; id < 3 * DIM; id += 256) {
            float A = g[id] * rsqrtf(v[id] + 1e-5f);
            affA[id] = A;
            affB[id] = (b1[id] - m[id]) * A + be[id];
        }
    }
}

// ---------------------------------------------------------------------------
// Per bucket: stage bucket into LDS once, redundant in-LDS scan of all 512
// bucket counts, local histogram -> scan -> off[] + csr[] (contiguous region).
// ---------------------------------------------------------------------------
__global__ __launch_bounds__(256) void bucket_fill(
    const unsigned* __restrict__ binned, const int* __restrict__ gpos,
    int* __restrict__ off, int* __restrict__ csr, int M)
{
    __shared__ unsigned bl[BCAP];
    __shared__ int sc[NBKT];
    __shared__ int cntL[256];
    __shared__ int sh[256];
    __shared__ int posL[256];
    const int b = blockIdx.x;
    const int t = threadIdx.x;

    // scan 512 clamped counts with 256 threads (Hillis-Steele, 2 elems/thread)
    sc[t]       = min(gpos[t], BCAP);
    sc[t + 256] = min(gpos[t + 256], BCAP);
    const int nb = min(gpos[b], BCAP);
    __syncthreads();
    for (int ofs = 1; ofs < NBKT; ofs <<= 1) {
        int a0 = (t >= ofs) ? sc[t - ofs] : 0;
        int a1 = sc[t + 256 - ofs];
        __syncthreads();
        sc[t] += a0; sc[t + 256] += a1;
        __syncthreads();
    }
    const int base = sc[b] - nb;          // exclusive prefix

    // stage bucket into LDS
    for (int i = t; i < nb; i += 256)
        bl[i] = binned[(size_t)b * BCAP + i];
    cntL[t] = 0;
    __syncthreads();
    for (int i = t; i < nb; i += 256)
        atomicAdd(&cntL[bl[i] & 255], 1);
    __syncthreads();
    sh[t] = cntL[t];
    __syncthreads();
    #pragma unroll
    for (int ofs = 1; ofs < 256; ofs <<= 1) {
        int add = (t >= ofs) ? sh[t - ofs] : 0;
        __syncthreads();
        sh[t] += add;
        __syncthreads();
    }
    int excl = sh[t] - cntL[t];
    int node = b * 256 + t;
    if (node <= M) off[node] = base + excl;
    posL[t] = excl;
    __syncthreads();
    for (int i = t; i < nb; i += 256) {
        unsigned vv = bl[i];
        int slot = atomicAdd(&posL[vv & 255], 1);
        csr[base + slot] = (int)(vv >> 8);
    }
}

// ---------------------------------------------------------------------------
// Vectorized CSR gather (R8, unchanged — measured at the random-access
// service-rate roofline: FETCH=188 MB ~= 8 XCD x 25.6 MB floor, dur 63.5 us).
// ---------------------------------------------------------------------------
__device__ __forceinline__ void addpair(float2& a, unsigned v) {
    float2 p = bfpair2f(v);
    a.x += p.x; a.y += p.y;
}

__global__ __launch_bounds__(256) void gather_v(
    const uint4* __restrict__ Hv,      // bf16 rows, 16 uint4 per row
    const int* __restrict__ off, const int* __restrict__ csr,
    uint4* __restrict__ AGv, int M)
{
    int node = (blockIdx.x * 256 + threadIdx.x) >> 6;
    if (node >= M) return;
    int lane = threadIdx.x & 63;
    int q = lane >> 4, li = lane & 15;

    float2 acc[4];
    acc[0] = acc[1] = acc[2] = acc[3] = make_float2(0.f, 0.f);
    if (q == 0) {                       // self term (GIN eps=0)
        uint4 w = Hv[(size_t)node * 16 + li];
        acc[0] = bfpair2f(w.x); acc[1] = bfpair2f(w.y);
        acc[2] = bfpair2f(w.z); acc[3] = bfpair2f(w.w);
    }

    const int beg = off[node], end = off[node + 1];
    for (int jb = beg; jb < end; jb += 32) {
        int idx[8];
        uint4 w[8];
        #pragma unroll
        for (int u = 0; u < 8; ++u) {
            idx[u] = jb + u * 4 + q;
            int ic = idx[u] < end ? idx[u] : end - 1;
            int s = csr[ic];
            w[u] = Hv[(size_t)s * 16 + li];
        }
        #pragma unroll
        for (int u = 0; u < 8; ++u) {
            if (idx[u] >= end) { w[u].x = 0; w[u].y = 0; w[u].z = 0; w[u].w = 0; }
            addpair(acc[0], w[u].x);
            addpair(acc[1], w[u].y);
            addpair(acc[2], w[u].z);
            addpair(acc[3], w[u].w);
        }
    }

    #pragma unroll
    for (int k = 0; k < 4; ++k) {
        acc[k].x += __shfl_xor(acc[k].x, 16);
        acc[k].y += __shfl_xor(acc[k].y, 16);
        acc[k].x += __shfl_xor(acc[k].x, 32);
        acc[k].y += __shfl_xor(acc[k].y, 32);
    }
    if (q == 0) {
        uint4 o;
        o.x = (unsigned)f2bf(acc[0].x) | ((unsigned)f2bf(acc[0].y) << 16);
        o.y = (unsigned)f2bf(acc[1].x) | ((unsigned)f2bf(acc[1].y) << 16);
        o.z = (unsigned)f2bf(acc[2].x) | ((unsigned)f2bf(acc[2].y) << 16);
        o.w = (unsigned)f2bf(acc[3].x) | ((unsigned)f2bf(acc[3].y) << 16);
        AGv[(size_t)node * 16 + li] = o;
    }
}

// ---------------------------------------------------------------------------
// Fused GEMM pair v2: A-fragments read DIRECTLY from global (prefetched 4x16B
// per wave before the W1-stage barrier) — no A LDS staging. H1 round-trips
// through a small own-wave LDS buffer. 3 barriers total.
// OOB rows (gr>=M) read garbage from the allocated buffer beyond row M (input
// is always Q, which is followed by P in the workspace) — MFMA rows are
// independent and stores are guarded, so garbage never escapes.
// ---------------------------------------------------------------------------
template<int LAST>
__global__ __launch_bounds__(256) void fused_layer(
    const unsigned short* __restrict__ AGGb,
    const unsigned short* __restrict__ W1t,
    const unsigned short* __restrict__ W2t,
    const float* __restrict__ affA, const float* __restrict__ affB,
    const float* __restrict__ b2, void* __restrict__ OUTp, int M)
{
    __shared__ unsigned short H1s[64 * ASTR];
    __shared__ unsigned short Wsub[128 * WSTR];
    const int t = threadIdx.x;
    const int row0 = blockIdx.x * 64;
    const int w = t >> 6;
    const int lane = t & 63;
    const int lm = lane & 15;
    const int quad = lane >> 4;

    // --- prefetch A fragments (4 independent 16-B global loads) ---
    const unsigned short* ap = AGGb + (size_t)(row0 + w * 16 + lm) * DIM;
    bf16x8 afr[4];
    #pragma unroll
    for (int kc = 0; kc < 4; ++kc)
        afr[kc] = *(const bf16x8*)(ap + kc * 32 + quad * 8);

    // --- stage W1^T: 128 rows x 32 ushort4 chunks = 4096 ---
    #pragma unroll
    for (int i = 0; i < 16; ++i) {
        int idx = t + 256 * i;
        int n = idx >> 5, kc = idx & 31;
        *(ushort4*)&Wsub[n * WSTR + kc * 4] = ((const ushort4*)W1t)[idx];
    }
    __syncthreads();

    f32x4 acc[8];
    #pragma unroll
    for (int i = 0; i < 8; ++i) { f32x4 z = {0.f, 0.f, 0.f, 0.f}; acc[i] = z; }
    #pragma unroll
    for (int kc = 0; kc < 4; ++kc) {
        int k0 = kc * 32 + quad * 8;
        bf16x8 a = afr[kc];
        #pragma unroll
        for (int tt = 0; tt < 8; ++tt) {
            bf16x8 b = *(const bf16x8*)&Wsub[(tt * 16 + lm) * WSTR + k0];
            acc[tt] = __builtin_amdgcn_mfma_f32_16x16x32_bf16(a, b, acc[tt], 0, 0, 0);
        }
    }

    // --- epilogue 1: BN affine + relu -> H1 (bf16) into own rows of H1s ---
    #pragma unroll
    for (int tt = 0; tt < 8; ++tt) {
        int c = tt * 16 + lm;
        float aA = affA[c], aB = affB[c];
        #pragma unroll
        for (int r = 0; r < 4; ++r) {
            float h = fmaxf(acc[tt][r] * aA + aB, 0.f);
            H1s[(w * 16 + quad * 4 + r) * ASTR + c] = f2bf(h);
        }
    }
    __syncthreads();   // all W1 reads done -> Wsub reusable
    // --- restage W2^T ---
    #pragma unroll
    for (int i = 0; i < 16; ++i) {
        int idx = t + 256 * i;
        int n = idx >> 5, kc = idx & 31;
        *(ushort4*)&Wsub[n * WSTR + kc * 4] = ((const ushort4*)W2t)[idx];
    }
    __syncthreads();

    const int arow = w * 16 + lm;
    f32x4 acc2[8];
    #pragma unroll
    for (int i = 0; i < 8; ++i) { f32x4 z = {0.f, 0.f, 0.f, 0.f}; acc2[i] = z; }
    #pragma unroll
    for (int kc = 0; kc < 4; ++kc) {
        int k0 = kc * 32 + quad * 8;
        bf16x8 a = *(const bf16x8*)&H1s[arow * ASTR + k0];
        #pragma unroll
        for (int tt = 0; tt < 8; ++tt) {
            bf16x8 b = *(const bf16x8*)&Wsub[(tt * 16 + lm) * WSTR + k0];
            acc2[tt] = __builtin_amdgcn_mfma_f32_16x16x32_bf16(a, b, acc2[tt], 0, 0, 0);
        }
    }

    // --- epilogue 2: +b2, relu; bf16 store or fused in-wave log_softmax ---
    float v[8][4];
    #pragma unroll
    for (int tt = 0; tt < 8; ++tt) {
        int c = tt * 16 + lm;
        float bb = b2[c];
        #pragma unroll
        for (int r = 0; r < 4; ++r)
            v[tt][r] = fmaxf(acc2[tt][r] + bb, 0.f);
    }

    if (!LAST) {
        unsigned short* OUT = (unsigned short*)OUTp;
        #pragma unroll
        for (int tt = 0; tt < 8; ++tt) {
            int c = tt * 16 + lm;
            #pragma unroll
            for (int r = 0; r < 4; ++r) {
                int gr = row0 + w * 16 + quad * 4 + r;
                if (gr < M) OUT[(size_t)gr * DIM + c] = f2bf(v[tt][r]);
            }
        }
    } else {
        // Row r lives on the 16 lanes sharing this quad (butterfly over lm).
        float* OUT = (float*)OUTp;
        #pragma unroll
        for (int r = 0; r < 4; ++r) {
            float mm = v[0][r];
            #pragma unroll
            for (int tt = 1; tt < 8; ++tt) mm = fmaxf(mm, v[tt][r]);
            #pragma unroll
            for (int ofs = 1; ofs < 16; ofs <<= 1)
                mm = fmaxf(mm, __shfl_xor(mm, ofs));
            float ss = 0.f;
            #pragma unroll
            for (int tt = 0; tt < 8; ++tt) ss += __expf(v[tt][r] - mm);
            #pragma unroll
            for (int ofs = 1; ofs < 16; ofs <<= 1)
                ss += __shfl_xor(ss, ofs);
            float lse = mm + __logf(ss);
            int gr = row0 + w * 16 + quad * 4 + r;
            if (gr < M) {
                #pragma unroll
                for (int tt = 0; tt < 8; ++tt)
                    OUT[(size_t)gr * DIM + tt * 16 + lm] = v[tt][r] - lse;
            }
        }
    }
}

// ---------------------------------------------------------------------------
static inline size_t align256(size_t v) { return (v + 255) & ~(size_t)255; }

extern "C" void kernel_launch(void* const* d_in, const int* in_sizes, int n_in,
                              void* d_out, int out_size, void* d_ws, size_t ws_size,
                              hipStream_t stream) {
    const float*    x     = (const float*)d_in[0];
    const unsigned* eidx  = (const unsigned*)d_in[1];
    const float*    W1    = (const float*)d_in[2];
    const float*    b1    = (const float*)d_in[3];
    const float*    gamma = (const float*)d_in[4];
    const float*    beta  = (const float*)d_in[5];
    const float*    rmean = (const float*)d_in[6];
    const float*    rvar  = (const float*)d_in[7];
    const float*    W2    = (const float*)d_in[8];
    const float*    b2    = (const float*)d_in[9];

    const int M = in_sizes[0] / DIM;        // 100000
    const int E = in_sizes[1] / 2;          // 1600000
    const size_t hbf_bytes = (size_t)M * DIM * 2;

    float* out = (float*)d_out;
    char*  ws  = (char*)d_ws;

    // Workspace (~58 MB). Q precedes P so fused_layer's bounded A-overread
    // past row M (max 8 KB) lands in allocated P.
    size_t o = 0;
    unsigned short* Wt = (unsigned short*)(ws + o); o = align256(o + (size_t)3 * 2 * 16384 * 2);
    float* affA = (float*)(ws + o);                 o = align256(o + 3 * DIM * 4);
    float* affB = (float*)(ws + o);                 o = align256(o + 3 * DIM * 4);
    int* gpos  = (int*)(ws + o);                    o = align256(o + NBKT * 4);
    int* off   = (int*)(ws + o);                    o = align256(o + ((size_t)M + 1) * 4);
    int* csr   = (int*)(ws + o);                    o = align256(o + (size_t)E * 4);
    unsigned short* Q = (unsigned short*)(ws + o);  o = align256(o + hbf_bytes);
    unsigned short* P = (unsigned short*)(ws + o);  o = align256(o + hbf_bytes);
    // binned (512*4608*4 = 9.4 MB) aliases Q: fully consumed by bucket_fill
    // before the first gather writes Q.
    unsigned* binned = (unsigned*)Q;

    const int bblk = (E + ECHUNK - 1) / ECHUNK;     // 640
    const int xblk = (M * 32 + 255) / 256;          // 12500
    const int wblk = (3 * 2 * 16384 + 255) / 256;   // 384

    hipMemsetAsync(gpos, 0, NBKT * 4, stream);
    prep_bin<<<bblk + xblk + wblk + 1, 256, 0, stream>>>(
        x, W1, W2, b1, gamma, beta, rmean, rvar, eidx,
        Wt, affA, affB, (u16x4*)P, gpos, binned, M, E, bblk, xblk, wblk);
    bucket_fill<<<NBKT, 256, 0, stream>>>(binned, gpos, off, csr, M);

    const int gat_blocks  = (M + 3) / 4;
    const int fuse_blocks = (M + 63) / 64;

    // Layer 0: P -> Q -> P
    gather_v<<<gat_blocks, 256, 0, stream>>>((const uint4*)P, off, csr,
                                             (uint4*)Q, M);
    fused_layer<0><<<fuse_blocks, 256, 0, stream>>>(
        Q, Wt + 0 * 16384, Wt + 1 * 16384,
        affA + 0 * DIM, affB + 0 * DIM, b2 + 0 * DIM, (void*)P, M);
    // Layer 1: P -> Q -> P
    gather_v<<<gat_blocks, 256, 0, stream>>>((const uint4*)P, off, csr,
                                             (uint4*)Q, M);
    fused_layer<0><<<fuse_blocks, 256, 0, stream>>>(
        Q, Wt + 2 * 16384, Wt + 3 * 16384,
        affA + 1 * DIM, affB + 1 * DIM, b2 + 1 * DIM, (void*)P, M);
    // Layer 2: P -> Q -> out (fp32 + fused log_softmax)
    gather_v<<<gat_blocks, 256, 0, stream>>>((const uint4*)P, off, csr,
                                             (uint4*)Q, M);
    fused_layer<1><<<fuse_blocks, 256, 0, stream>>>(
        Q, Wt + 4 * 16384, Wt + 5 * 16384,
        affA + 2 * DIM, affB + 2 * DIM, b2 + 2 * DIM, (void*)out, M);
}